// Round 11
// baseline (166.012 us; speedup 1.0000x reference)
//
#include <hip/hip_runtime.h>

// VQ-VAE vector quantizer. Round 11.
// z: [16,64,32,32] f32, emb: [8192,64] f32. N=16384 pts, C=64, V=8192.
// out = [ z_q_st (1048576) | idx as f32 (16384) | vq_loss (1) ]
//
// R10 post-mortem: k1 stuck at ~50us, VALU-issue-bound with bloat (index-
// tracked top-2 = 4-5 instr/score + 8 acc-init movs + AGPR round-trips).
// R11: INDEX PACKED INTO SCORE MANTISSA (low 13 bits = 8191-code) -> top-2
// update = pack+med3+max = 3 instr/score, no index regs; -h folded into the
// MFMA C operand (nhv4, kills acc-init movs); h pre-negated + LDS-staged;
// pt=4, SPLITS=16 (1024 blocks, 4 waves/SIMD, B-ingest 1MB/CU).
// Packing perturbs scores by <= 2^13 ulp (~0.0625 at |s|<64); THR raised to
// 0.22 so all affected points go to exact-fp32 rescue.

typedef _Float16 half8 __attribute__((ext_vector_type(8)));
typedef float f32x4 __attribute__((ext_vector_type(4)));

#define N_PTS 16384
#define SPLITS 16
#define THR 0.22f

// e16 swizzled (halfs): per-wave B-frag load (tile T):
// e16 + vbase*64 + T*1024 + lane*8 -> contiguous 1KB,
// giving B[n=lane&15][k=(lane>>4)*8+j].

// ---------------- k_pre: emb -> swizzled fp16 + fp32 transpose, -norms -------
__global__ __launch_bounds__(256) void k_pre(const float* __restrict__ emb,
                                             float* __restrict__ hneg,
                                             unsigned short* __restrict__ e16,
                                             float* __restrict__ embT,
                                             int* __restrict__ cnt) {
  int v = blockIdx.x * 256 + threadIdx.x;   // grid 32 -> 8192
  const float4* e4 = (const float4*)(emb + v * 64);
  float s = 0.f;
  float row[64];
#pragma unroll
  for (int i = 0; i < 16; ++i) {
    float4 a = e4[i];
    row[i * 4 + 0] = a.x; row[i * 4 + 1] = a.y;
    row[i * 4 + 2] = a.z; row[i * 4 + 3] = a.w;
    s += a.x * a.x + a.y * a.y + a.z * a.z + a.w * a.w;
  }
  unsigned short* base = e16 + (v >> 4) * 1024 + (v & 15) * 8;
#pragma unroll
  for (int c8 = 0; c8 < 8; ++c8) {
    half8 o;
#pragma unroll
    for (int j = 0; j < 8; ++j) o[j] = (_Float16)row[c8 * 8 + j];
    *(half8*)(base + (c8 >> 2) * 512 + (c8 & 3) * 128) = o;
  }
  // fp32 transpose: embT[c][v]; consecutive lanes -> consecutive v: coalesced
#pragma unroll
  for (int c = 0; c < 64; ++c) embT[c * 8192 + v] = row[c];
  hneg[v] = -0.5f * s;
  if (v == 0) *cnt = 0;
}

// ---------------- k1: MFMA scores, packed-index top-2, pt=4 ----------------
// grid (64, 16). block 256 = 4 waves; wave owns 64 points (4 tiles of 16),
// sweeps 512 codes (32 tiles). 1024 blocks = 4 blocks/CU = 4 waves/SIMD.
__global__ __launch_bounds__(256, 4) void k1_score(
    const float* __restrict__ z, const unsigned short* __restrict__ e16,
    const float* __restrict__ hneg,
    float* __restrict__ ps, float* __restrict__ p2) {
  __shared__ float hs[512];
  const int tid = threadIdx.x;
  const int lane = tid & 63;
  const int wid = tid >> 6;
  const int cl = lane & 15;     // A row (point) / B col (code) within tile
  const int gq = lane >> 4;     // quad: selects k-slice / C rows
  const int n0 = blockIdx.x * 256 + wid * 64;
  const int split = blockIdx.y;
  const int vbase = split * 512;

  // stage -h chunk (512 floats) once
  *(float2*)&hs[tid * 2] = *(const float2*)(hneg + vbase + tid * 2);
  __syncthreads();

  const int b = n0 >> 10;
  const int hw0 = n0 & 1023;

  // A frags: A[pt][H]  with A[m=cl][k=gq*8+j], half H = channels H*32..+31
  half8 A[4][2];
  {
    const float* zb = z + b * 65536 + hw0 + cl;
#pragma unroll
    for (int pt = 0; pt < 4; ++pt)
#pragma unroll
      for (int H = 0; H < 2; ++H) {
        half8 a;
#pragma unroll
        for (int j = 0; j < 8; ++j)
          a[j] = (_Float16)zb[pt * 16 + (H * 32 + gq * 8 + j) * 1024];
        A[pt][H] = a;
      }
  }

  float s1[4][4], s2[4][4];
#pragma unroll
  for (int pt = 0; pt < 4; ++pt)
#pragma unroll
    for (int r = 0; r < 4; ++r) { s1[pt][r] = -3.0e38f; s2[pt][r] = -3.0e38f; }

  const unsigned short* bbase = e16 + vbase * 64 + lane * 8;
  int idxb = 8191 - (vbase + cl);   // packed-index field, decrements 16/tile

#pragma unroll 2
  for (int T = 0; T < 32; ++T) {
    const unsigned short* bp = bbase + T * 1024;
    half8 B0 = *(const half8*)bp;
    half8 B1 = *(const half8*)(bp + 512);
    const float nh = hs[T * 16 + cl];
    f32x4 C0;
    C0[0] = nh; C0[1] = nh; C0[2] = nh; C0[3] = nh;   // -h as MFMA C operand

#pragma unroll
    for (int pt = 0; pt < 4; ++pt) {
      f32x4 acc = __builtin_amdgcn_mfma_f32_16x16x32_f16(A[pt][0], B0, C0, 0, 0, 0);
      acc = __builtin_amdgcn_mfma_f32_16x16x32_f16(A[pt][1], B1, acc, 0, 0, 0);

      // packed top-2: 3 instr/score (and_or, med3, max); lower code wins ties
#pragma unroll
      for (int r = 0; r < 4; ++r) {
        unsigned u = (__float_as_uint(acc[r]) & 0xFFFFE000u) | (unsigned)idxb;
        float p = __uint_as_float(u);
        s2[pt][r] = __builtin_amdgcn_fmed3f(p, s1[pt][r], s2[pt][r]);
        s1[pt][r] = fmaxf(s1[pt][r], p);
      }
    }
    idxb -= 16;
  }

  // butterfly merge across the 16 cols (index rides inside s1/s2)
#pragma unroll
  for (int off = 8; off >= 1; off >>= 1) {
#pragma unroll
    for (int pt = 0; pt < 4; ++pt)
#pragma unroll
      for (int r = 0; r < 4; ++r) {
        float os = __shfl_xor(s1[pt][r], off);
        float o2 = __shfl_xor(s2[pt][r], off);
        s2[pt][r] = fmaxf(fmaxf(s2[pt][r], o2), fminf(s1[pt][r], os));
        s1[pt][r] = fmaxf(s1[pt][r], os);
      }
  }

  if (cl == 0) {
#pragma unroll
    for (int pt = 0; pt < 4; ++pt)
#pragma unroll
      for (int r = 0; r < 4; ++r) {
        int n = n0 + pt * 16 + gq * 4 + r;     // C row = gq*4 + reg
        int o = split * N_PTS + n;
        ps[o] = s1[pt][r]; p2[o] = s2[pt][r];
      }
  }
}

// ---------------- k2: merge splits (packed), margin test, emit idx ----------
__global__ __launch_bounds__(256) void k2_merge(
    const float* __restrict__ ps, const float* __restrict__ p2,
    int* __restrict__ idxf, float* __restrict__ out_idx,
    int* __restrict__ list, int* __restrict__ cnt) {
  int n = blockIdx.x * 256 + threadIdx.x;   // grid 64 -> 16384
  float S1 = ps[n], S2 = p2[n];
#pragma unroll
  for (int s = 1; s < SPLITS; ++s) {
    int o = s * N_PTS + n;
    float a = ps[o], a2 = p2[o];
    if (a > S1) { S2 = fmaxf(fmaxf(S2, a2), S1); S1 = a; }
    else        { S2 = fmaxf(S2, a); }
  }
  int I1 = 8191 - (int)(__float_as_uint(S1) & 0x1FFFu);
  idxf[n] = I1;
  out_idx[n] = (float)I1;
  if (S1 - S2 < THR) {
    int p = atomicAdd(cnt, 1);
    list[p] = n;
  }
}

// ---------------- k_rescue: exact fp32, 1024 thr, 8 codes/thr, 4 pts/blk ----
__global__ __launch_bounds__(1024, 4) void k_rescue(
    const float* __restrict__ z, const float* __restrict__ embT,
    const float* __restrict__ hneg, const int* __restrict__ list,
    const int* __restrict__ cnt,
    int* __restrict__ idxf, float* __restrict__ out_idx) {
  __shared__ float zsT[64][4];
  __shared__ int pn[4];
  __shared__ float rs[16][4], ri[16][4];
  const int tid = threadIdx.x;
  const int lane = tid & 63, wv = tid >> 6;
  const int count = *cnt;

  for (int base = blockIdx.x * 4; base < count; base += gridDim.x * 4) {
    const int P = min(4, count - base);
    __syncthreads();
    if (tid < 4) pn[tid] = list[base + min(tid, P - 1)];  // pad with last valid
    __syncthreads();
    if (tid < 256) {
      int p = tid >> 6, c = tid & 63;
      int n = pn[p];
      zsT[c][p] = z[(n >> 10) * 65536 + c * 1024 + (n & 1023)];
    }
    __syncthreads();

    float d[32];
#pragma unroll
    for (int i = 0; i < 32; ++i) d[i] = 0.f;

    const float4* eT = (const float4*)embT;   // rows of 2048 float4
    float4 cur0 = eT[tid];                    // c=0, codes 4t..4t+3
    float4 cur1 = eT[1024 + tid];             // c=0, codes 4096+4t..+3

    for (int c = 0; c < 64; ++c) {
      float4 nxt0, nxt1;
      if (c < 63) {
        const float4* rowp = eT + (c + 1) * 2048 + tid;
        nxt0 = rowp[0];
        nxt1 = rowp[1024];
      }
      float4 zp = *(const float4*)&zsT[c][0];   // broadcast, conflict-free
      float ev[8] = {cur0.x, cur0.y, cur0.z, cur0.w,
                     cur1.x, cur1.y, cur1.z, cur1.w};
#pragma unroll
      for (int k = 0; k < 8; ++k) {
        d[k * 4 + 0] = fmaf(ev[k], zp.x, d[k * 4 + 0]);
        d[k * 4 + 1] = fmaf(ev[k], zp.y, d[k * 4 + 1]);
        d[k * 4 + 2] = fmaf(ev[k], zp.z, d[k * 4 + 2]);
        d[k * 4 + 3] = fmaf(ev[k], zp.w, d[k * 4 + 3]);
      }
      if (c < 63) { cur0 = nxt0; cur1 = nxt1; }
    }

    // per-thread argmax per point over its 8 codes (code-ascending, strict >)
    float4 hv0 = *(const float4*)(hneg + tid * 4);
    float4 hv1 = *(const float4*)(hneg + 4096 + tid * 4);
    float bs[4], bi[4];
#pragma unroll
    for (int p = 0; p < 4; ++p) { bs[p] = -3.0e38f; bi[p] = 0.f; }
#pragma unroll
    for (int k = 0; k < 8; ++k) {
      float hk = (k == 0) ? hv0.x : (k == 1) ? hv0.y : (k == 2) ? hv0.z :
                 (k == 3) ? hv0.w : (k == 4) ? hv1.x : (k == 5) ? hv1.y :
                 (k == 6) ? hv1.z : hv1.w;
      float cf = (float)((k < 4 ? 0 : 4096) + tid * 4 + (k & 3));
#pragma unroll
      for (int p = 0; p < 4; ++p) {
        float sc = d[k * 4 + p] + hk;
        if (sc > bs[p]) { bs[p] = sc; bi[p] = cf; }
      }
    }

    // wave butterfly (disjoint code sets; tie -> lower code), then cross-wave
#pragma unroll
    for (int off = 32; off >= 1; off >>= 1) {
#pragma unroll
      for (int p = 0; p < 4; ++p) {
        float os = __shfl_xor(bs[p], off);
        float oi = __shfl_xor(bi[p], off);
        if (os > bs[p] || (os == bs[p] && oi < bi[p])) { bs[p] = os; bi[p] = oi; }
      }
    }
    if (lane == 0)
#pragma unroll
      for (int p = 0; p < 4; ++p) { rs[wv][p] = bs[p]; ri[wv][p] = bi[p]; }
    __syncthreads();
    if (tid < 4) {
      int p = tid;
      float s = rs[0][p], i = ri[0][p];
#pragma unroll
      for (int w = 1; w < 16; ++w) {
        if (rs[w][p] > s || (rs[w][p] == s && ri[w][p] < i)) { s = rs[w][p]; i = ri[w][p]; }
      }
      if (p < P) {
        int n = pn[p];
        idxf[n] = (int)i;
        out_idx[n] = i;
      }
    }
  }
}

// ---------------- k3: gather, straight-through out, block partial loss --------
__global__ __launch_bounds__(256) void k3_quant(
    const float* __restrict__ z, const float* __restrict__ emb,
    const int* __restrict__ idxf,
    float* __restrict__ out, float* __restrict__ psum) {
  int t = blockIdx.x * 256 + threadIdx.x;   // grid 1024 -> 262144 float4 slots
  int g = t * 4;
  int b = g >> 16;
  int c = (g >> 10) & 63;
  int hw = g & 1023;
  int n = (b << 10) | hw;                   // n..n+3, 4-aligned
  float4 zv = *(const float4*)(z + g);
  int4 iv = *(const int4*)(idxf + n);
  float q0 = emb[iv.x * 64 + c];
  float q1 = emb[iv.y * 64 + c];
  float q2 = emb[iv.z * 64 + c];
  float q3 = emb[iv.w * 64 + c];
  float d0 = q0 - zv.x, d1 = q1 - zv.y, d2 = q2 - zv.z, d3 = q3 - zv.w;
  float4 o;
  o.x = zv.x + d0; o.y = zv.y + d1; o.z = zv.z + d2; o.w = zv.w + d3;
  *(float4*)(out + g) = o;
  float val = d0 * d0 + d1 * d1 + d2 * d2 + d3 * d3;
#pragma unroll
  for (int off = 32; off >= 1; off >>= 1) val += __shfl_down(val, off);
  __shared__ float wsum[4];
  int lane = threadIdx.x & 63, wv = threadIdx.x >> 6;
  if (lane == 0) wsum[wv] = val;
  __syncthreads();
  if (threadIdx.x == 0)
    psum[blockIdx.x] = wsum[0] + wsum[1] + wsum[2] + wsum[3];
}

// ---------------- k4: final loss reduce (1024 partials) ----------------
__global__ __launch_bounds__(256) void k4_loss(const float* __restrict__ psum,
                                               float* __restrict__ out_loss) {
  int tid = threadIdx.x;
  float val = psum[tid] + psum[tid + 256] + psum[tid + 512] + psum[tid + 768];
#pragma unroll
  for (int off = 32; off >= 1; off >>= 1) val += __shfl_down(val, off);
  __shared__ float wsum[4];
  int lane = tid & 63, wv = tid >> 6;
  if (lane == 0) wsum[wv] = val;
  __syncthreads();
  if (tid == 0)
    out_loss[0] = 1.25f * (wsum[0] + wsum[1] + wsum[2] + wsum[3]) * (1.0f / 1048576.0f);
}

extern "C" void kernel_launch(void* const* d_in, const int* in_sizes, int n_in,
                              void* d_out, int out_size, void* d_ws, size_t ws_size,
                              hipStream_t stream) {
  const float* z   = (const float*)d_in[0];
  const float* emb = (const float*)d_in[1];
  float* out = (float*)d_out;
  float* ws  = (float*)d_ws;

  float* hneg = ws;                                   // 8192
  unsigned short* e16 = (unsigned short*)(ws + 8192); // 524288 halfs = 262144 f
  float* embT = ws + 8192 + 262144;                   // 524288 (fp32 transpose)
  float* ps  = embT + 524288;                         // 16*16384
  float* p2  = ps + SPLITS * N_PTS;                   // 16*16384
  int* idxf  = (int*)(p2 + SPLITS * N_PTS);           // 16384
  int* list  = idxf + N_PTS;                          // 16384
  int* cnt   = list + N_PTS;                          // 1
  float* psum = (float*)(cnt + 1);                    // 1024

  float* out_idx  = out + 1048576;
  float* out_loss = out + 1048576 + 16384;

  k_pre<<<32, 256, 0, stream>>>(emb, hneg, e16, embT, cnt);
  k1_score<<<dim3(64, SPLITS), 256, 0, stream>>>(z, e16, hneg, ps, p2);
  k2_merge<<<64, 256, 0, stream>>>(ps, p2, idxf, out_idx, list, cnt);
  k_rescue<<<256, 1024, 0, stream>>>(z, embT, hneg, list, cnt, idxf, out_idx);
  k3_quant<<<1024, 256, 0, stream>>>(z, emb, idxf, out, psum);
  k4_loss<<<1, 256, 0, stream>>>(psum, out_loss);
}

// Round 12
// 157.709 us; speedup vs baseline: 1.0526x; 1.0526x over previous
//
#include <hip/hip_runtime.h>

// VQ-VAE vector quantizer. Round 12.
// z: [16,64,32,32] f32, emb: [8192,64] f32. N=16384 pts, C=64, V=8192.
// out = [ z_q_st (1048576) | idx as f32 (16384) | vq_loss (1) ]
//
// R11 post-mortem: packed-index top-2 fixed k1, but blanket THR=0.22
// inflated rescue count >1024 -> 2 serial 2MB sweeps/block = 54us.
// R12: (a) k2 compensates packing error EXACTLY per point: truncation error
// <= |S|*2^-10, so rescue iff S1-S2 < 0.08 + q, q = max(|S1|,|S2|)*2^-10
// -> count back to ~single-sweep territory.
// (b) rescue batches 8 pts/block (64 accs, ~100 live VGPR under (1024,4))
// -> one FMA-bound sweep ~14us instead of latency-bound 54.

typedef _Float16 half8 __attribute__((ext_vector_type(8)));
typedef float f32x4 __attribute__((ext_vector_type(4)));

#define N_PTS 16384
#define SPLITS 16
#define THR16 0.08f   // fp16-score error bound (10 sigma), validated R3-R11

// e16 swizzled (halfs): per-wave B-frag load (tile T):
// e16 + vbase*64 + T*1024 + lane*8 -> contiguous 1KB,
// giving B[n=lane&15][k=(lane>>4)*8+j].

// ---------------- k_pre: emb -> swizzled fp16 + fp32 transpose, -norms -------
__global__ __launch_bounds__(256) void k_pre(const float* __restrict__ emb,
                                             float* __restrict__ hneg,
                                             unsigned short* __restrict__ e16,
                                             float* __restrict__ embT,
                                             int* __restrict__ cnt) {
  int v = blockIdx.x * 256 + threadIdx.x;   // grid 32 -> 8192
  const float4* e4 = (const float4*)(emb + v * 64);
  float s = 0.f;
  float row[64];
#pragma unroll
  for (int i = 0; i < 16; ++i) {
    float4 a = e4[i];
    row[i * 4 + 0] = a.x; row[i * 4 + 1] = a.y;
    row[i * 4 + 2] = a.z; row[i * 4 + 3] = a.w;
    s += a.x * a.x + a.y * a.y + a.z * a.z + a.w * a.w;
  }
  unsigned short* base = e16 + (v >> 4) * 1024 + (v & 15) * 8;
#pragma unroll
  for (int c8 = 0; c8 < 8; ++c8) {
    half8 o;
#pragma unroll
    for (int j = 0; j < 8; ++j) o[j] = (_Float16)row[c8 * 8 + j];
    *(half8*)(base + (c8 >> 2) * 512 + (c8 & 3) * 128) = o;
  }
  // fp32 transpose: embT[c][v]; consecutive lanes -> consecutive v: coalesced
#pragma unroll
  for (int c = 0; c < 64; ++c) embT[c * 8192 + v] = row[c];
  hneg[v] = -0.5f * s;
  if (v == 0) *cnt = 0;
}

// ---------------- k1: MFMA scores, packed-index top-2, pt=4 ----------------
// grid (64, 16). block 256 = 4 waves; wave owns 64 points (4 tiles of 16),
// sweeps 512 codes (32 tiles). 1024 blocks = 4 blocks/CU = 4 waves/SIMD.
__global__ __launch_bounds__(256, 4) void k1_score(
    const float* __restrict__ z, const unsigned short* __restrict__ e16,
    const float* __restrict__ hneg,
    float* __restrict__ ps, float* __restrict__ p2) {
  __shared__ float hs[512];
  const int tid = threadIdx.x;
  const int lane = tid & 63;
  const int wid = tid >> 6;
  const int cl = lane & 15;     // A row (point) / B col (code) within tile
  const int gq = lane >> 4;     // quad: selects k-slice / C rows
  const int n0 = blockIdx.x * 256 + wid * 64;
  const int split = blockIdx.y;
  const int vbase = split * 512;

  // stage -h chunk (512 floats) once
  *(float2*)&hs[tid * 2] = *(const float2*)(hneg + vbase + tid * 2);
  __syncthreads();

  const int b = n0 >> 10;
  const int hw0 = n0 & 1023;

  // A frags: A[pt][H]  with A[m=cl][k=gq*8+j], half H = channels H*32..+31
  half8 A[4][2];
  {
    const float* zb = z + b * 65536 + hw0 + cl;
#pragma unroll
    for (int pt = 0; pt < 4; ++pt)
#pragma unroll
      for (int H = 0; H < 2; ++H) {
        half8 a;
#pragma unroll
        for (int j = 0; j < 8; ++j)
          a[j] = (_Float16)zb[pt * 16 + (H * 32 + gq * 8 + j) * 1024];
        A[pt][H] = a;
      }
  }

  float s1[4][4], s2[4][4];
#pragma unroll
  for (int pt = 0; pt < 4; ++pt)
#pragma unroll
    for (int r = 0; r < 4; ++r) { s1[pt][r] = -3.0e38f; s2[pt][r] = -3.0e38f; }

  const unsigned short* bbase = e16 + vbase * 64 + lane * 8;
  int idxb = 8191 - (vbase + cl);   // packed-index field, decrements 16/tile

#pragma unroll 2
  for (int T = 0; T < 32; ++T) {
    const unsigned short* bp = bbase + T * 1024;
    half8 B0 = *(const half8*)bp;
    half8 B1 = *(const half8*)(bp + 512);
    const float nh = hs[T * 16 + cl];
    f32x4 C0;
    C0[0] = nh; C0[1] = nh; C0[2] = nh; C0[3] = nh;   // -h as MFMA C operand

#pragma unroll
    for (int pt = 0; pt < 4; ++pt) {
      f32x4 acc = __builtin_amdgcn_mfma_f32_16x16x32_f16(A[pt][0], B0, C0, 0, 0, 0);
      acc = __builtin_amdgcn_mfma_f32_16x16x32_f16(A[pt][1], B1, acc, 0, 0, 0);

      // packed top-2: 3 instr/score (and_or, med3, max); lower code wins ties
#pragma unroll
      for (int r = 0; r < 4; ++r) {
        unsigned u = (__float_as_uint(acc[r]) & 0xFFFFE000u) | (unsigned)idxb;
        float p = __uint_as_float(u);
        s2[pt][r] = __builtin_amdgcn_fmed3f(p, s1[pt][r], s2[pt][r]);
        s1[pt][r] = fmaxf(s1[pt][r], p);
      }
    }
    idxb -= 16;
  }

  // butterfly merge across the 16 cols (index rides inside s1/s2)
#pragma unroll
  for (int off = 8; off >= 1; off >>= 1) {
#pragma unroll
    for (int pt = 0; pt < 4; ++pt)
#pragma unroll
      for (int r = 0; r < 4; ++r) {
        float os = __shfl_xor(s1[pt][r], off);
        float o2 = __shfl_xor(s2[pt][r], off);
        s2[pt][r] = fmaxf(fmaxf(s2[pt][r], o2), fminf(s1[pt][r], os));
        s1[pt][r] = fmaxf(s1[pt][r], os);
      }
  }

  if (cl == 0) {
#pragma unroll
    for (int pt = 0; pt < 4; ++pt)
#pragma unroll
      for (int r = 0; r < 4; ++r) {
        int n = n0 + pt * 16 + gq * 4 + r;     // C row = gq*4 + reg
        int o = split * N_PTS + n;
        ps[o] = s1[pt][r]; p2[o] = s2[pt][r];
      }
  }
}

// ---------------- k2: merge splits (packed), exact-q margin, emit idx --------
__global__ __launch_bounds__(256) void k2_merge(
    const float* __restrict__ ps, const float* __restrict__ p2,
    int* __restrict__ idxf, float* __restrict__ out_idx,
    int* __restrict__ list, int* __restrict__ cnt) {
  int n = blockIdx.x * 256 + threadIdx.x;   // grid 64 -> 16384
  float S1 = ps[n], S2 = p2[n];
#pragma unroll
  for (int s = 1; s < SPLITS; ++s) {
    int o = s * N_PTS + n;
    float a = ps[o], a2 = p2[o];
    if (a > S1) { S2 = fmaxf(fmaxf(S2, a2), S1); S1 = a; }
    else        { S2 = fmaxf(S2, a); }
  }
  int I1 = 8191 - (int)(__float_as_uint(S1) & 0x1FFFu);
  idxf[n] = I1;
  out_idx[n] = (float)I1;
  // packing truncation error <= |S|*2^-10 per score; compensate exactly
  float q = fmaxf(fabsf(S1), fabsf(S2)) * 0.0009765625f;
  if (S1 - S2 < THR16 + q) {
    int p = atomicAdd(cnt, 1);
    list[p] = n;
  }
}

// ---------------- k_rescue: exact fp32, 1024 thr, 8 codes/thr, 8 pts/blk ----
// Thread t owns codes {4t..4t+3, 4096+4t..4096+4t+3}; 8 points share the
// sweep (d[8 codes][8 pts] = 64 accs). Single sweep for count <= 2048.
__global__ __launch_bounds__(1024, 4) void k_rescue(
    const float* __restrict__ z, const float* __restrict__ embT,
    const float* __restrict__ hneg, const int* __restrict__ list,
    const int* __restrict__ cnt,
    int* __restrict__ idxf, float* __restrict__ out_idx) {
  __shared__ float zsT[64][8];
  __shared__ int pn[8];
  __shared__ float rs[16][8], ri[16][8];
  const int tid = threadIdx.x;
  const int lane = tid & 63, wv = tid >> 6;
  const int count = *cnt;

  for (int base = blockIdx.x * 8; base < count; base += gridDim.x * 8) {
    const int P = min(8, count - base);
    __syncthreads();
    if (tid < 8) pn[tid] = list[base + min(tid, P - 1)];  // pad with last valid
    __syncthreads();
    if (tid < 512) {
      int p = tid >> 6, c = tid & 63;
      int n = pn[p];
      zsT[c][p] = z[(n >> 10) * 65536 + c * 1024 + (n & 1023)];
    }
    __syncthreads();

    float d[64];
#pragma unroll
    for (int i = 0; i < 64; ++i) d[i] = 0.f;

    const float4* eT = (const float4*)embT;   // rows of 2048 float4
    float4 cur0 = eT[tid];                    // c=0, codes 4t..4t+3
    float4 cur1 = eT[1024 + tid];             // c=0, codes 4096+4t..+3

    for (int c = 0; c < 64; ++c) {
      float4 nxt0, nxt1;
      if (c < 63) {
        const float4* rowp = eT + (c + 1) * 2048 + tid;
        nxt0 = rowp[0];
        nxt1 = rowp[1024];
      }
      float4 zpA = *(const float4*)&zsT[c][0];   // broadcast, conflict-free
      float4 zpB = *(const float4*)&zsT[c][4];
#pragma unroll
      for (int k = 0; k < 8; ++k) {
        float e = (k == 0) ? cur0.x : (k == 1) ? cur0.y : (k == 2) ? cur0.z :
                  (k == 3) ? cur0.w : (k == 4) ? cur1.x : (k == 5) ? cur1.y :
                  (k == 6) ? cur1.z : cur1.w;
        float* dp = d + k * 8;
        dp[0] = fmaf(e, zpA.x, dp[0]); dp[1] = fmaf(e, zpA.y, dp[1]);
        dp[2] = fmaf(e, zpA.z, dp[2]); dp[3] = fmaf(e, zpA.w, dp[3]);
        dp[4] = fmaf(e, zpB.x, dp[4]); dp[5] = fmaf(e, zpB.y, dp[5]);
        dp[6] = fmaf(e, zpB.z, dp[6]); dp[7] = fmaf(e, zpB.w, dp[7]);
      }
      if (c < 63) { cur0 = nxt0; cur1 = nxt1; }
    }

    // per-thread argmax per point over its 8 codes (code-ascending, strict >)
    float4 hv0 = *(const float4*)(hneg + tid * 4);
    float4 hv1 = *(const float4*)(hneg + 4096 + tid * 4);
    float bs[8], bi[8];
#pragma unroll
    for (int p = 0; p < 8; ++p) { bs[p] = -3.0e38f; bi[p] = 0.f; }
#pragma unroll
    for (int k = 0; k < 8; ++k) {
      float hk = (k == 0) ? hv0.x : (k == 1) ? hv0.y : (k == 2) ? hv0.z :
                 (k == 3) ? hv0.w : (k == 4) ? hv1.x : (k == 5) ? hv1.y :
                 (k == 6) ? hv1.z : hv1.w;
      float cf = (float)((k < 4 ? 0 : 4096) + tid * 4 + (k & 3));
#pragma unroll
      for (int p = 0; p < 8; ++p) {
        float sc = d[k * 8 + p] + hk;
        if (sc > bs[p]) { bs[p] = sc; bi[p] = cf; }
      }
    }

    // wave butterfly (disjoint code sets; tie -> lower code), then cross-wave
#pragma unroll
    for (int off = 32; off >= 1; off >>= 1) {
#pragma unroll
      for (int p = 0; p < 8; ++p) {
        float os = __shfl_xor(bs[p], off);
        float oi = __shfl_xor(bi[p], off);
        if (os > bs[p] || (os == bs[p] && oi < bi[p])) { bs[p] = os; bi[p] = oi; }
      }
    }
    if (lane == 0)
#pragma unroll
      for (int p = 0; p < 8; ++p) { rs[wv][p] = bs[p]; ri[wv][p] = bi[p]; }
    __syncthreads();
    if (tid < 8) {
      int p = tid;
      float s = rs[0][p], i = ri[0][p];
#pragma unroll
      for (int w = 1; w < 16; ++w) {
        if (rs[w][p] > s || (rs[w][p] == s && ri[w][p] < i)) { s = rs[w][p]; i = ri[w][p]; }
      }
      if (p < P) {
        int n = pn[p];
        idxf[n] = (int)i;
        out_idx[n] = i;
      }
    }
  }
}

// ---------------- k3: gather, straight-through out, block partial loss --------
__global__ __launch_bounds__(256) void k3_quant(
    const float* __restrict__ z, const float* __restrict__ emb,
    const int* __restrict__ idxf,
    float* __restrict__ out, float* __restrict__ psum) {
  int t = blockIdx.x * 256 + threadIdx.x;   // grid 1024 -> 262144 float4 slots
  int g = t * 4;
  int b = g >> 16;
  int c = (g >> 10) & 63;
  int hw = g & 1023;
  int n = (b << 10) | hw;                   // n..n+3, 4-aligned
  float4 zv = *(const float4*)(z + g);
  int4 iv = *(const int4*)(idxf + n);
  float q0 = emb[iv.x * 64 + c];
  float q1 = emb[iv.y * 64 + c];
  float q2 = emb[iv.z * 64 + c];
  float q3 = emb[iv.w * 64 + c];
  float d0 = q0 - zv.x, d1 = q1 - zv.y, d2 = q2 - zv.z, d3 = q3 - zv.w;
  float4 o;
  o.x = zv.x + d0; o.y = zv.y + d1; o.z = zv.z + d2; o.w = zv.w + d3;
  *(float4*)(out + g) = o;
  float val = d0 * d0 + d1 * d1 + d2 * d2 + d3 * d3;
#pragma unroll
  for (int off = 32; off >= 1; off >>= 1) val += __shfl_down(val, off);
  __shared__ float wsum[4];
  int lane = threadIdx.x & 63, wv = threadIdx.x >> 6;
  if (lane == 0) wsum[wv] = val;
  __syncthreads();
  if (threadIdx.x == 0)
    psum[blockIdx.x] = wsum[0] + wsum[1] + wsum[2] + wsum[3];
}

// ---------------- k4: final loss reduce (1024 partials) ----------------
__global__ __launch_bounds__(256) void k4_loss(const float* __restrict__ psum,
                                               float* __restrict__ out_loss) {
  int tid = threadIdx.x;
  float val = psum[tid] + psum[tid + 256] + psum[tid + 512] + psum[tid + 768];
#pragma unroll
  for (int off = 32; off >= 1; off >>= 1) val += __shfl_down(val, off);
  __shared__ float wsum[4];
  int lane = tid & 63, wv = tid >> 6;
  if (lane == 0) wsum[wv] = val;
  __syncthreads();
  if (tid == 0)
    out_loss[0] = 1.25f * (wsum[0] + wsum[1] + wsum[2] + wsum[3]) * (1.0f / 1048576.0f);
}

extern "C" void kernel_launch(void* const* d_in, const int* in_sizes, int n_in,
                              void* d_out, int out_size, void* d_ws, size_t ws_size,
                              hipStream_t stream) {
  const float* z   = (const float*)d_in[0];
  const float* emb = (const float*)d_in[1];
  float* out = (float*)d_out;
  float* ws  = (float*)d_ws;

  float* hneg = ws;                                   // 8192
  unsigned short* e16 = (unsigned short*)(ws + 8192); // 524288 halfs = 262144 f
  float* embT = ws + 8192 + 262144;                   // 524288 (fp32 transpose)
  float* ps  = embT + 524288;                         // 16*16384
  float* p2  = ps + SPLITS * N_PTS;                   // 16*16384
  int* idxf  = (int*)(p2 + SPLITS * N_PTS);           // 16384
  int* list  = idxf + N_PTS;                          // 16384
  int* cnt   = list + N_PTS;                          // 1
  float* psum = (float*)(cnt + 1);                    // 1024

  float* out_idx  = out + 1048576;
  float* out_loss = out + 1048576 + 16384;

  k_pre<<<32, 256, 0, stream>>>(emb, hneg, e16, embT, cnt);
  k1_score<<<dim3(64, SPLITS), 256, 0, stream>>>(z, e16, hneg, ps, p2);
  k2_merge<<<64, 256, 0, stream>>>(ps, p2, idxf, out_idx, list, cnt);
  k_rescue<<<256, 1024, 0, stream>>>(z, embT, hneg, list, cnt, idxf, out_idx);
  k3_quant<<<1024, 256, 0, stream>>>(z, emb, idxf, out, psum);
  k4_loss<<<1, 256, 0, stream>>>(psum, out_loss);
}